// Round 9
// baseline (98.720 us; speedup 1.0000x reference)
//
#include <hip/hip_runtime.h>

typedef _Float16 f16x8 __attribute__((ext_vector_type(8)));
typedef float f32x4 __attribute__((ext_vector_type(4)));

__device__ __forceinline__ f16x8 splat8(float v) {
  _Float16 h = (_Float16)v;
  return f16x8{h, h, h, h, h, h, h, h};
}

// ------- Kernel 1: x NCHW f32 -> xt NHWC f16 (1024 blks) + weight prep (216 blks) -------
__global__ __launch_bounds__(256) void k_xtprep(const float* __restrict__ x,
                                                const float* __restrict__ wt,
                                                const float* __restrict__ ow,
                                                _Float16* __restrict__ xt,
                                                _Float16* __restrict__ wb,
                                                _Float16* __restrict__ owb) {
  __shared__ float tile[64 * 65];
  int blk = blockIdx.x;
  int t = threadIdx.x;
  if (blk < 1024) {
    int b = blk >> 8;
    int y = (blk >> 1) & 127;
    int w0 = (blk & 1) * 64;
    const float* xp = x + ((size_t)(b * 64) * 128 + y) * 128 + w0;
#pragma unroll
    for (int it = 0; it < 4; ++it) {
      int idx = it * 256 + t;
      int c = idx >> 4, q = idx & 15;
      float4 v = *(const float4*)(xp + (size_t)c * 16384 + q * 4);
      float* tp = &tile[c * 65 + q * 4];
      tp[0] = v.x; tp[1] = v.y; tp[2] = v.z; tp[3] = v.w;
    }
    __syncthreads();
#pragma unroll
    for (int it = 0; it < 2; ++it) {
      int idx = it * 256 + t;
      int w = idx >> 3, c8 = idx & 7;
      f16x8 o;
#pragma unroll
      for (int j = 0; j < 8; ++j) o[j] = (_Float16)tile[(c8 * 8 + j) * 65 + w];
      *(f16x8*)&xt[(((size_t)b * 128 + y) * 128 + w0 + w) * 64 + c8 * 8] = o;
    }
  } else {
    int i = (blk - 1024) * 256 + t;
    if (i < 36864) {
      int k = i >> 12, rem = i & 4095, o = rem >> 6, c = rem & 63;
      wb[i] = (_Float16)wt[(o * 64 + c) * 9 + k];
    } else if (i < 36864 + 18432) {
      int j = i - 36864;
      int k = j >> 11, rem = j & 2047, o = rem >> 6, c = rem & 63;
      float v = (o < 18) ? ow[(o * 64 + c) * 9 + k] : 0.0f;
      owb[j] = (_Float16)v;
    }
  }
}

// ---------------- Kernel 2: fused deformable conv, one-shot sampling ----------------
// grid 2048 = (4 wtiles of 32px) x (128 h) x (4 b), XCD-chunk swizzled; 256 thr.
// Stage0: 3x34x64c -> Xs (LDS). bar.
// Phase A: offset conv MFMA (B from Xs) -> offL. bar.
// Sampling: 288 (tap,px) pairs, one thread each: 32 independent gathers + f16
//   interp -> S[288][72] (ONE latency exposure, no barriers inside). bar.
// MFMA sweep: K=576 in one pass: 36 MFMAs/wave, B ds_read from S, A from wb.
__global__ __launch_bounds__(256, 3) void k_fused(
    const _Float16* __restrict__ xt, const _Float16* __restrict__ wb,
    const _Float16* __restrict__ owb, const float* __restrict__ ob,
    const float* __restrict__ bias, float* __restrict__ out) {
  __shared__ char lds[288 * 72 * 2 + 32 * 20 * 4];  // 41472 + 2560 = 44032 B
  _Float16* Xs = (_Float16*)lds;        // [3*34][72], aliases S
  _Float16* S = (_Float16*)lds;         // [288][72]
  float* offL = (float*)(lds + 41472);  // [32][20]

  int t = threadIdx.x;
  // XCD-chunked bijective swizzle: 2048 blocks = 8 XCDs x 256 chunks
  int lb = (blockIdx.x & 7) * 256 + (blockIdx.x >> 3);
  int w0 = (lb & 3) * 32;
  int h = (lb >> 2) & 127;
  int b = lb >> 9;

  int lane = t & 63, wid = t >> 6;
  int row = lane & 15, quad = lane >> 4;
  const _Float16* xb = xt + (size_t)b * 128 * 128 * 64;

  // ======= Stage0: rows h-1..h+1, px w0-1..w0+32 (34), all 64c =======
#pragma unroll
  for (int it = 0; it < 4; ++it) {
    int idx8 = it * 256 + t;  // 816 chunks of f16x8
    if (idx8 < 816) {
      int c8 = idx8 & 7;
      int jr = idx8 >> 3;  // 0..101
      int jj = jr % 34;
      int ki = jr / 34;
      int gy = h - 1 + ki;
      int gx = w0 - 1 + jj;
      f16x8 v = {};
      if (((unsigned)gy < 128u) & ((unsigned)gx < 128u))
        v = *(const f16x8*)(xb + ((size_t)gy * 128 + gx) * 64 + c8 * 8);
      *(f16x8*)&Xs[(ki * 34 + jj) * 72 + c8 * 8] = v;
    }
  }
  __syncthreads();

  // ======= Phase A: offset conv MFMA (M=18pad32, N=32px, K=576) =======
  {
    int woA = (wid >> 1) * 16;
    int wpA = (wid & 1) * 16;
    f32x4 accA = f32x4{0.f, 0.f, 0.f, 0.f};
#pragma unroll
    for (int k = 0; k < 9; ++k) {
      int ki = k / 3, kj = k % 3;
      const _Float16* ap = owb + k * 2048 + (woA + row) * 64 + quad * 8;
      f16x8 afr0 = *(const f16x8*)(ap);
      f16x8 afr1 = *(const f16x8*)(ap + 32);
      int j = wpA + row + kj;  // 0..33
      const _Float16* lp = &Xs[(ki * 34 + j) * 72 + quad * 8];
      f16x8 b0 = *(const f16x8*)(lp);
      f16x8 b1 = *(const f16x8*)(lp + 32);
      accA = __builtin_amdgcn_mfma_f32_16x16x32_f16(afr0, b0, accA, 0, 0, 0);
      accA = __builtin_amdgcn_mfma_f32_16x16x32_f16(afr1, b1, accA, 0, 0, 0);
    }
    int qr = quad * 4;
#pragma unroll
    for (int r = 0; r < 4; ++r) {
      int co = woA + qr + r;
      if (co < 18) offL[(wpA + row) * 20 + co] = accA[r] + ob[co];
    }
  }
  __syncthreads();  // Xs dead, offL ready -> S may be written

  // ======= One-shot sampling: 288 (tap,px) pairs -> S[tap*32+px][72] =======
#pragma unroll
  for (int rep = 0; rep < 2; ++rep) {
    int p = rep * 256 + t;
    if (p < 288) {
      int tap = p >> 5, px = p & 31;
      int w = w0 + px;
      float dy = offL[px * 20 + 2 * tap];
      float dx = offL[px * 20 + 2 * tap + 1];
      float py = dy + (float)(h + tap / 3 - 1);
      float pxf = dx + (float)(w + tap % 3 - 1);
      float fy = floorf(py), fx = floorf(pxf);
      float ly = py - fy, lx = pxf - fx;
      int y0 = (int)fy, x0 = (int)fx;
      int y1 = y0 + 1, x1 = x0 + 1;
      bool vy0 = (unsigned)y0 < 128u, vy1 = (unsigned)y1 < 128u;
      bool vx0 = (unsigned)x0 < 128u, vx1 = (unsigned)x1 < 128u;
      float w00 = (vy0 && vx0) ? (1.f - ly) * (1.f - lx) : 0.f;
      float w01 = (vy0 && vx1) ? (1.f - ly) * lx : 0.f;
      float w10 = (vy1 && vx0) ? ly * (1.f - lx) : 0.f;
      float w11 = (vy1 && vx1) ? ly * lx : 0.f;
      int yc0 = min(max(y0, 0), 127), yc1 = min(max(y1, 0), 127);
      int xc0 = min(max(x0, 0), 127), xc1 = min(max(x1, 0), 127);
      const _Float16* p00 = xb + (yc0 * 128 + xc0) * 64;
      int dxo = (xc1 - xc0) * 64;
      int dyo = (yc1 - yc0) * 8192;
      // 32 independent gathers (4 corners x 8 chunks) — single latency exposure
      f16x8 g0[8], g1[8], g2[8], g3[8];
#pragma unroll
      for (int j = 0; j < 8; ++j) {
        g0[j] = *(const f16x8*)(p00 + j * 8);
        g1[j] = *(const f16x8*)(p00 + dxo + j * 8);
        g2[j] = *(const f16x8*)(p00 + dyo + j * 8);
        g3[j] = *(const f16x8*)(p00 + dyo + dxo + j * 8);
      }
      f16x8 W00 = splat8(w00), W01 = splat8(w01);
      f16x8 W10 = splat8(w10), W11 = splat8(w11);
      _Float16* Srow = &S[(tap * 32 + px) * 72];
#pragma unroll
      for (int j = 0; j < 8; ++j) {
        f16x8 s = W00 * g0[j] + W01 * g1[j] + W10 * g2[j] + W11 * g3[j];
        *(f16x8*)&Srow[j * 8] = s;
      }
    }
  }
  __syncthreads();

  // ======= MFMA sweep: 64o x 32px tile, K=576 in one unrolled pass =======
  int woB = (wid >> 1) * 32, wpB = (wid & 1) * 16;
  f32x4 acc[2];
  acc[0] = f32x4{0.f, 0.f, 0.f, 0.f};
  acc[1] = f32x4{0.f, 0.f, 0.f, 0.f};
#pragma unroll
  for (int tap = 0; tap < 9; ++tap) {
    const _Float16* wk = wb + tap * 4096;
#pragma unroll
    for (int ks = 0; ks < 2; ++ks) {
      int c0 = ks * 32 + quad * 8;
      f16x8 bfr = *(const f16x8*)&S[(tap * 32 + wpB + row) * 72 + c0];
#pragma unroll
      for (int mi = 0; mi < 2; ++mi) {
        f16x8 afr = *(const f16x8*)(wk + (woB + mi * 16 + row) * 64 + c0);
        acc[mi] = __builtin_amdgcn_mfma_f32_16x16x32_f16(afr, bfr, acc[mi], 0, 0, 0);
      }
    }
  }
  // epilogue: col=lane&15 (px), o = woB + mi*16 + quad*4 + r
  {
    int qr = quad * 4;
#pragma unroll
    for (int mi = 0; mi < 2; ++mi) {
#pragma unroll
      for (int r = 0; r < 4; ++r) {
        int o = woB + mi * 16 + qr + r;
        out[(((size_t)b * 64 + o) * 128 + h) * 128 + w0 + wpB + row] =
            acc[mi][r] + bias[o];
      }
    }
  }
}

extern "C" void kernel_launch(void* const* d_in, const int* in_sizes, int n_in,
                              void* d_out, int out_size, void* d_ws,
                              size_t ws_size, hipStream_t stream) {
  const float* x = (const float*)d_in[0];       // (4,64,128,128)
  const float* ow = (const float*)d_in[1];      // (18,64,3,3)
  const float* ob = (const float*)d_in[2];      // (18,)
  const float* wt = (const float*)d_in[3];      // (64,64,3,3)
  const float* bias = (const float*)d_in[4];    // (64,)
  float* out = (float*)d_out;                   // (4,64,128,128)

  char* ws = (char*)d_ws;
  _Float16* xt = (_Float16*)ws;                      // 8,388,608 B
  _Float16* wb = (_Float16*)(ws + 8388608);          // 73,728 B
  _Float16* owb = (_Float16*)(ws + 8388608 + 73728); // 36,864 B

  k_xtprep<<<1240, 256, 0, stream>>>(x, wt, ow, xt, wb, owb);
  k_fused<<<2048, 256, 0, stream>>>(xt, wb, owb, ob, bias, out);
}

// Round 10
// 40.433 us; speedup vs baseline: 2.4416x; 2.4416x over previous
//
#include <hip/hip_runtime.h>

typedef _Float16 f16x8 __attribute__((ext_vector_type(8)));
typedef float f32x4 __attribute__((ext_vector_type(4)));

__device__ __forceinline__ f16x8 splat8(float v) {
  _Float16 h = (_Float16)v;
  return f16x8{h, h, h, h, h, h, h, h};
}

// ------- Kernel 1: x NCHW f32 -> xt NHWC f16 (1024 blks) + weight prep (216 blks) -------
__global__ __launch_bounds__(256) void k_xtprep(const float* __restrict__ x,
                                                const float* __restrict__ wt,
                                                const float* __restrict__ ow,
                                                _Float16* __restrict__ xt,
                                                _Float16* __restrict__ wb,
                                                _Float16* __restrict__ owb) {
  __shared__ float tile[64 * 65];
  int blk = blockIdx.x;
  int t = threadIdx.x;
  if (blk < 1024) {
    int b = blk >> 8;
    int y = (blk >> 1) & 127;
    int w0 = (blk & 1) * 64;
    const float* xp = x + ((size_t)(b * 64) * 128 + y) * 128 + w0;
#pragma unroll
    for (int it = 0; it < 4; ++it) {
      int idx = it * 256 + t;
      int c = idx >> 4, q = idx & 15;
      float4 v = *(const float4*)(xp + (size_t)c * 16384 + q * 4);
      float* tp = &tile[c * 65 + q * 4];
      tp[0] = v.x; tp[1] = v.y; tp[2] = v.z; tp[3] = v.w;
    }
    __syncthreads();
#pragma unroll
    for (int it = 0; it < 2; ++it) {
      int idx = it * 256 + t;
      int w = idx >> 3, c8 = idx & 7;
      f16x8 o;
#pragma unroll
      for (int j = 0; j < 8; ++j) o[j] = (_Float16)tile[(c8 * 8 + j) * 65 + w];
      *(f16x8*)&xt[(((size_t)b * 128 + y) * 128 + w0 + w) * 64 + c8 * 8] = o;
    }
  } else {
    int i = (blk - 1024) * 256 + t;
    if (i < 36864) {
      int k = i >> 12, rem = i & 4095, o = rem >> 6, c = rem & 63;
      wb[i] = (_Float16)wt[(o * 64 + c) * 9 + k];
    } else if (i < 36864 + 18432) {
      int j = i - 36864;
      int k = j >> 11, rem = j & 2047, o = rem >> 6, c = rem & 63;
      float v = (o < 18) ? ow[(o * 64 + c) * 9 + k] : 0.0f;
      owb[j] = (_Float16)v;
    }
  }
}

// ---------------- Kernel 2: fused deformable conv, R1-pattern ----------------
// grid 1024 = (2 wtiles of 64px) x (128 h) x (4 b), XCD-chunk swizzled; 256 thr.
// ALL MFMA operands come from LDS; weight slices cooperatively staged per tap.
// Phase A: Xs-staged input + owb dbuf-staged per tap, 1 bar/tap.
// Phase B (R1-proven): per tap {stage Wk + sample S; bar; 8 MFMA/wave; bar}.
__global__ __launch_bounds__(256, 4) void k_fused(
    const _Float16* __restrict__ xt, const _Float16* __restrict__ wb,
    const _Float16* __restrict__ owb, const float* __restrict__ ob,
    const float* __restrict__ bias, float* __restrict__ out) {
  // LDS: [S 64x72 | WkL 64x72 | offL 64x20 f32] aliased by Xs[198x72];
  //      owbkL[2][32x72] disjoint. Total 37,728 B -> 4 blocks/CU.
  __shared__ char lds[37728];
  _Float16* S = (_Float16*)lds;                  // Phase B: [64][72]
  _Float16* WkL = (_Float16*)(lds + 9216);       // Phase B: [64][72]
  float* offL = (float*)(lds + 18432);           // [64][20]
  _Float16* Xs = (_Float16*)lds;                 // Phase A: [198][72]
  _Float16* owbkL = (_Float16*)(lds + 28512);    // [2][32*72]

  int t = threadIdx.x;
  int lb = (blockIdx.x & 7) * 128 + (blockIdx.x >> 3);  // 1024 = 8 XCDs x 128
  int w0 = (lb & 1) * 64;
  int h = (lb >> 1) & 127;
  int b = lb >> 8;

  int lane = t & 63, wid = t >> 6;
  int row = lane & 15, quad = lane >> 4;
  const _Float16* xb = xt + (size_t)b * 128 * 128 * 64;

  // ======= Stage: Xs (rows h-1..h+1, px w0-1..w0+64, 64c) + owb tap0 =======
#pragma unroll
  for (int it = 0; it < 8; ++it) {
    int idx8 = it * 256 + t;  // 1584 Xs chunks + 256 owbk chunks
    if (idx8 < 1584) {
      int c8 = idx8 & 7;
      int jr = idx8 >> 3;  // 0..197
      int jj = jr % 66;
      int ki = jr / 66;
      int gy = h - 1 + ki;
      int gx = w0 - 1 + jj;
      f16x8 v = {};
      if (((unsigned)gy < 128u) & ((unsigned)gx < 128u))
        v = *(const f16x8*)(xb + ((size_t)gy * 128 + gx) * 64 + c8 * 8);
      *(f16x8*)&Xs[(ki * 66 + jj) * 72 + c8 * 8] = v;
    } else if (idx8 < 1840) {
      int j = idx8 - 1584;  // 0..255: owb tap 0, [32][64] -> [32][72]
      int o = j >> 3, c8 = j & 7;
      *(f16x8*)&owbkL[o * 72 + c8 * 8] = *(const f16x8*)(owb + j * 8);
    }
  }
  __syncthreads();

  // ======= Phase A: offset conv, A from owbkL (dbuf), B from Xs =======
  {
    int woA = (wid >> 1) * 16;  // 0 or 16
    int wpA = (wid & 1) * 32;   // 0 or 32
    f32x4 accA[2];
    accA[0] = f32x4{0.f, 0.f, 0.f, 0.f};
    accA[1] = f32x4{0.f, 0.f, 0.f, 0.f};
#pragma unroll
    for (int k = 0; k < 9; ++k) {
      // stage owb tap k+1 into the other buffer
      if (k < 8) {
        int o = t >> 3, c8 = t & 7;
        *(f16x8*)&owbkL[((k + 1) & 1) * 2304 + o * 72 + c8 * 8] =
            *(const f16x8*)(owb + (k + 1) * 2048 + t * 8);
      }
      int ki = k / 3, kj = k % 3;
      const _Float16* ap = &owbkL[(k & 1) * 2304 + (woA + row) * 72 + quad * 8];
      f16x8 afr0 = *(const f16x8*)(ap);
      f16x8 afr1 = *(const f16x8*)(ap + 32);
#pragma unroll
      for (int n = 0; n < 2; ++n) {
        int j = wpA + n * 16 + row + kj;  // 0..65
        const _Float16* lp = &Xs[(ki * 66 + j) * 72 + quad * 8];
        f16x8 b0 = *(const f16x8*)(lp);
        f16x8 b1 = *(const f16x8*)(lp + 32);
        accA[n] = __builtin_amdgcn_mfma_f32_16x16x32_f16(afr0, b0, accA[n], 0, 0, 0);
        accA[n] = __builtin_amdgcn_mfma_f32_16x16x32_f16(afr1, b1, accA[n], 0, 0, 0);
      }
      __syncthreads();
    }
    // offL aliases Xs tail: all Xs reads are behind the last barrier. Write now.
    int qr = quad * 4;
#pragma unroll
    for (int n = 0; n < 2; ++n) {
#pragma unroll
      for (int r = 0; r < 4; ++r) {
        int co = woA + qr + r;
        if (co < 18)
          offL[(wpA + n * 16 + row) * 20 + co] = accA[n][r] + ob[co];
      }
    }
  }
  __syncthreads();

  // ======= Phase B: R1 structure — stage Wk + sample S; bar; MFMA; bar =======
  int pix = t >> 2, cg = t & 3;
  int w = w0 + pix;
  int woB = (wid >> 1) * 32, wpB = (wid & 1) * 32;

  f32x4 acc[2][2];
#pragma unroll
  for (int i = 0; i < 2; ++i)
#pragma unroll
    for (int j = 0; j < 2; ++j) acc[i][j] = f32x4{0.f, 0.f, 0.f, 0.f};

  for (int k = 0; k < 9; ++k) {
    // ---- stage Wk: wb[k][64][64] -> WkL[64][72] (coalesced, 2 chunks/thread) ----
    {
      const f16x8* src = (const f16x8*)(wb + k * 4096);
#pragma unroll
      for (int r = 0; r < 2; ++r) {
        int idx8 = r * 256 + t;
        int o = idx8 >> 3, c8 = idx8 & 7;
        *(f16x8*)&WkL[o * 72 + c8 * 8] = src[idx8];
      }
    }
    // ---- sample S[pix][c] for this tap ----
    {
      int ki = k / 3, kj = k % 3;
      float dy = offL[pix * 20 + 2 * k];
      float dx = offL[pix * 20 + 2 * k + 1];
      float py = dy + (float)(h + ki - 1);
      float pxf = dx + (float)(w + kj - 1);
      float fy = floorf(py), fx = floorf(pxf);
      float ly = py - fy, lx = pxf - fx;
      int y0 = (int)fy, x0 = (int)fx;
      int y1 = y0 + 1, x1 = x0 + 1;
      bool vy0 = (unsigned)y0 < 128u, vy1 = (unsigned)y1 < 128u;
      bool vx0 = (unsigned)x0 < 128u, vx1 = (unsigned)x1 < 128u;
      float w00 = (vy0 && vx0) ? (1.f - ly) * (1.f - lx) : 0.f;
      float w01 = (vy0 && vx1) ? (1.f - ly) * lx : 0.f;
      float w10 = (vy1 && vx0) ? ly * (1.f - lx) : 0.f;
      float w11 = (vy1 && vx1) ? ly * lx : 0.f;
      int yc0 = min(max(y0, 0), 127), yc1 = min(max(y1, 0), 127);
      int xc0 = min(max(x0, 0), 127), xc1 = min(max(x1, 0), 127);
      const _Float16* p00 = xb + (yc0 * 128 + xc0) * 64 + cg * 16;
      int dxo = (xc1 - xc0) * 64;
      int dyo = (yc1 - yc0) * 8192;
      f16x8 a0 = *(const f16x8*)(p00);
      f16x8 a1 = *(const f16x8*)(p00 + 8);
      f16x8 b0 = *(const f16x8*)(p00 + dxo);
      f16x8 b1 = *(const f16x8*)(p00 + dxo + 8);
      f16x8 c0v = *(const f16x8*)(p00 + dyo);
      f16x8 c1 = *(const f16x8*)(p00 + dyo + 8);
      f16x8 d0 = *(const f16x8*)(p00 + dyo + dxo);
      f16x8 d1 = *(const f16x8*)(p00 + dyo + dxo + 8);
      f16x8 W00 = splat8(w00), W01 = splat8(w01);
      f16x8 W10 = splat8(w10), W11 = splat8(w11);
      f16x8 s0 = W00 * a0 + W01 * b0 + W10 * c0v + W11 * d0;
      f16x8 s1 = W00 * a1 + W01 * b1 + W10 * c1 + W11 * d1;
      *(f16x8*)&S[pix * 72 + cg * 16] = s0;
      *(f16x8*)&S[pix * 72 + cg * 16 + 8] = s1;
    }
    __syncthreads();
    // ---- MFMA: all operands from LDS ----
    {
#pragma unroll
      for (int ks = 0; ks < 2; ++ks) {
        int c0 = ks * 32 + quad * 8;
        f16x8 afr[2], bfr[2];
#pragma unroll
        for (int mi = 0; mi < 2; ++mi)
          afr[mi] = *(const f16x8*)&WkL[(woB + mi * 16 + row) * 72 + c0];
#pragma unroll
        for (int ni = 0; ni < 2; ++ni)
          bfr[ni] = *(const f16x8*)&S[(wpB + ni * 16 + row) * 72 + c0];
#pragma unroll
        for (int mi = 0; mi < 2; ++mi)
#pragma unroll
          for (int ni = 0; ni < 2; ++ni)
            acc[mi][ni] = __builtin_amdgcn_mfma_f32_16x16x32_f16(
                afr[mi], bfr[ni], acc[mi][ni], 0, 0, 0);
      }
    }
    __syncthreads();
  }
  // ---- epilogue: col=lane&15 (pix), row=quad*4+r (o) ----
  {
    int col = lane & 15;
    int qr = quad * 4;
#pragma unroll
    for (int mi = 0; mi < 2; ++mi) {
#pragma unroll
      for (int ni = 0; ni < 2; ++ni) {
#pragma unroll
        for (int r = 0; r < 4; ++r) {
          int o = woB + mi * 16 + qr + r;
          int pw = w0 + wpB + ni * 16 + col;
          out[(((size_t)b * 64 + o) * 128 + h) * 128 + pw] = acc[mi][ni][r] + bias[o];
        }
      }
    }
  }
}

extern "C" void kernel_launch(void* const* d_in, const int* in_sizes, int n_in,
                              void* d_out, int out_size, void* d_ws,
                              size_t ws_size, hipStream_t stream) {
  const float* x = (const float*)d_in[0];       // (4,64,128,128)
  const float* ow = (const float*)d_in[1];      // (18,64,3,3)
  const float* ob = (const float*)d_in[2];      // (18,)
  const float* wt = (const float*)d_in[3];      // (64,64,3,3)
  const float* bias = (const float*)d_in[4];    // (64,)
  float* out = (float*)d_out;                   // (4,64,128,128)

  char* ws = (char*)d_ws;
  _Float16* xt = (_Float16*)ws;                      // 8,388,608 B
  _Float16* wb = (_Float16*)(ws + 8388608);          // 73,728 B
  _Float16* owb = (_Float16*)(ws + 8388608 + 73728); // 36,864 B

  k_xtprep<<<1240, 256, 0, stream>>>(x, wt, ow, xt, wb, owb);
  k_fused<<<1024, 256, 0, stream>>>(xt, wb, owb, ob, bias, out);
}